// Round 4
// baseline (129.866 us; speedup 1.0000x reference)
//
#include <hip/hip_runtime.h>
#include <cstddef>

// InfoNCE loss, B=8192, D=128.
// prep: normalize + bf16 cast + label/conf signs + self-dot
// sim:  256-row blocks, double-buffered LDS, T14 reg-staged pipeline
//       (WR -> LDG(g+2) -> sched_barrier -> compute -> barrier), bf16 MFMA,
//       exp + masked row-sums (tot/diff trick).
//       amdgpu_waves_per_eu(2,2): rounds 1-3 all lost to LLVM raising
//       occupancy on its own and spilling staging regs (34-105 MB HBM writes).
// fin:  per-row loss, mean over valid rows

#define DDIM 128
#define TEMP_SCALE 14.4269504088896340736f  // (1/0.1) * log2(e), folded into A-side
#define GROUPS 4                            // 128-col groups per block (y-chunk = 512 cols)
#define PADS 136   // shorts per LDS row (272 B): (17*row+seg)%8 balances banks exactly

typedef short s8bf __attribute__((ext_vector_type(8)));   // 8 bf16 (4 VGPRs)
typedef float f32x4 __attribute__((ext_vector_type(4)));

__device__ __forceinline__ unsigned short f2bf(float f) {
    unsigned int u = __float_as_uint(f);
    u += 0x7fffu + ((u >> 16) & 1u);
    return (unsigned short)(u >> 16);
}
__device__ __forceinline__ float bf2f(unsigned short h) {
    return __uint_as_float(((unsigned int)h) << 16);
}

// ---------------- prep: one wave per row ----------------
__global__ __launch_bounds__(256) void prep_kernel(
    const float* __restrict__ emb, const int* __restrict__ labels,
    const float* __restrict__ conf,
    short* __restrict__ Ea,   // bf16(SCALE * e)  (A-side, pre-scaled)
    short* __restrict__ Eb,   // bf16(e)          (B-side)
    float2* __restrict__ lh,  // (label +-1, sign(conf))
    float* __restrict__ sd,   // scaled self-dot (bf16-rounded), diag of sim*SCALE
    float* __restrict__ pos_sum, float* __restrict__ tot_sum, int B)
{
    int wave = threadIdx.x >> 6;
    int lane = threadIdx.x & 63;
    int row  = blockIdx.x * 4 + wave;
    if (row >= B) return;

    float2 x = ((const float2*)(emb + (size_t)row * DDIM))[lane];
    float ss = x.x * x.x + x.y * x.y;
    #pragma unroll
    for (int m = 32; m; m >>= 1) ss += __shfl_xor(ss, m);
    float inv = 1.0f / fmaxf(sqrtf(ss), 1e-12f);

    float e0 = x.x * inv, e1 = x.y * inv;
    unsigned short ea0 = f2bf(TEMP_SCALE * e0), ea1 = f2bf(TEMP_SCALE * e1);
    unsigned short eb0 = f2bf(e0),              eb1 = f2bf(e1);
    *(ushort2*)(Ea + (size_t)row * DDIM + lane * 2) = make_ushort2(ea0, ea1);
    *(ushort2*)(Eb + (size_t)row * DDIM + lane * 2) = make_ushort2(eb0, eb1);

    float p = bf2f(ea0) * bf2f(eb0) + bf2f(ea1) * bf2f(eb1);
    #pragma unroll
    for (int m = 32; m; m >>= 1) p += __shfl_xor(p, m);

    if (lane == 0) {
        sd[row] = p;
        float l = labels[row] ? 1.0f : -1.0f;
        float c = conf[row];
        float h = (c > 0.0f) ? 1.0f : ((c < 0.0f) ? -1.0f : 0.0f);
        lh[row] = make_float2(l, h);
        pos_sum[row] = 0.0f;
        tot_sum[row] = 0.0f;
    }
}

// ---------------- sim ----------------
// Block = 256 thr = 4 waves, owns 256 rows (wave w -> rows w*64..w*64+63, 4 row-tiles).
// Cols: 16 y-chunks of 512; 4 groups of 128 cols per chunk, double-buffered LDS.
// Steady state per group: WR staged regs (arrived one full phase ago) ->
// issue LDG(g+2) -> sched_barrier -> compute 8 col-tiles -> barrier.
#define MFMA16(A, Bf, C) __builtin_amdgcn_mfma_f32_16x16x32_bf16((A), (Bf), (C), 0, 0, 0)

__global__ __launch_bounds__(256) __attribute__((amdgpu_waves_per_eu(2, 2)))
void sim_kernel(
    const short* __restrict__ Ea, const short* __restrict__ Eb,
    const float2* __restrict__ lh,
    float* __restrict__ pos_sum, float* __restrict__ tot_sum)
{
    __shared__ short tile[2][128 * PADS];    // 2 x 34816 B
    __shared__ float2 lhCol[GROUPS * 128];   // 4 KB: all 512 cols of this y-chunk

    const int lane = threadIdx.x & 63;
    const int wave = threadIdx.x >> 6;
    const int l16  = lane & 15;
    const int quad = lane >> 4;
    const int rowBase = blockIdx.x * 256 + wave * 64;   // 4 row-tiles

    // A fragments (loop-invariant): A[m=l16][k=quad*8+j], contiguous b128
    s8bf a[4][4];
    #pragma unroll
    for (int t = 0; t < 4; ++t)
        #pragma unroll
        for (int k = 0; k < 4; ++k)
            a[t][k] = *(const s8bf*)(Ea + (size_t)(rowBase + t * 16 + l16) * DDIM + k * 32 + quad * 8);

    // C/D layout: col = lane&15, row = quad*4 + reg.  Conf sign per owned row:
    float hi[4][4];
    #pragma unroll
    for (int t = 0; t < 4; ++t)
        #pragma unroll
        for (int r = 0; r < 4; ++r)
            hi[t][r] = lh[rowBase + t * 16 + quad * 4 + r].y;

    float tt[4][4], dd[4][4];
    #pragma unroll
    for (int t = 0; t < 4; ++t)
        #pragma unroll
        for (int r = 0; r < 4; ++r) { tt[t][r] = 0.0f; dd[t][r] = 0.0f; }

    const int c0base = blockIdx.y * (GROUPS * 128);

    // hoist all 512 column lh once (visible after the prologue barrier)
    lhCol[threadIdx.x]       = lh[c0base + threadIdx.x];
    lhCol[256 + threadIdx.x] = lh[c0base + 256 + threadIdx.x];

    // staging registers (named; must never spill)
    int4 s0, s1, s2, s3, s4, s5, s6, s7;
    #define LDG(colbase) do { \
        const int4* gsrc = (const int4*)(Eb + (size_t)(colbase) * DDIM); \
        s0 = gsrc[0 * 256 + threadIdx.x]; \
        s1 = gsrc[1 * 256 + threadIdx.x]; \
        s2 = gsrc[2 * 256 + threadIdx.x]; \
        s3 = gsrc[3 * 256 + threadIdx.x]; \
        s4 = gsrc[4 * 256 + threadIdx.x]; \
        s5 = gsrc[5 * 256 + threadIdx.x]; \
        s6 = gsrc[6 * 256 + threadIdx.x]; \
        s7 = gsrc[7 * 256 + threadIdx.x]; \
    } while (0)

    #define WR1(buf, i, v) do { \
        int chunk = (i) * 256 + threadIdx.x; \
        *(int4*)(&tile[buf][(chunk >> 4) * PADS + (chunk & 15) * 8]) = (v); \
    } while (0)
    #define WRB(buf) do { \
        WR1(buf, 0, s0); WR1(buf, 1, s1); WR1(buf, 2, s2); WR1(buf, 3, s3); \
        WR1(buf, 4, s4); WR1(buf, 5, s5); WR1(buf, 6, s6); WR1(buf, 7, s7); \
    } while (0)

    // prologue: group0 -> buf0, group1 in flight
    LDG(c0base);
    WRB(0);
    LDG(c0base + 128);
    __builtin_amdgcn_sched_barrier(0);   // loads stay issued here
    __syncthreads();

    for (int g = 0; g < GROUPS; ++g) {
        const int cur = g & 1;

        if (g + 1 < GROUPS) {
            WRB(cur ^ 1);                          // s-regs arrived one phase ago
            if (g + 2 < GROUPS) LDG(c0base + (g + 2) * 128);
            __builtin_amdgcn_sched_barrier(0);     // don't sink loads into compute
        }

        const short* tbase = &tile[cur][0];
        #pragma unroll
        for (int ct = 0; ct < 8; ++ct) {
            const short* tb = tbase + (ct * 16 + l16) * PADS + quad * 8;
            s8bf b0 = *(const s8bf*)(tb +  0);
            s8bf b1 = *(const s8bf*)(tb + 32);
            s8bf b2 = *(const s8bf*)(tb + 64);
            s8bf b3 = *(const s8bf*)(tb + 96);
            float2 lhj = lhCol[g * 128 + ct * 16 + l16];

            #pragma unroll
            for (int t = 0; t < 4; ++t) {
                f32x4 acc;
                #pragma unroll
                for (int r = 0; r < 4; ++r)   // conf mask folded into acc init
                    acc[r] = (hi[t][r] * lhj.y > 0.0f) ? 0.0f : -1e30f;
                acc = MFMA16(a[t][0], b0, acc);
                acc = MFMA16(a[t][1], b1, acc);
                acc = MFMA16(a[t][2], b2, acc);
                acc = MFMA16(a[t][3], b3, acc);
                #pragma unroll
                for (int r = 0; r < 4; ++r) {
                    float e = __builtin_amdgcn_exp2f(acc[r]);
                    tt[t][r] += e;
                    dd[t][r] = fmaf(lhj.x, e, dd[t][r]);   // row-label deferred
                }
            }
        }
        if (g + 1 < GROUPS) __syncthreads();   // all waves done reading before overwrite
    }

    // ---- reduce over the 16 column-lanes, one atomic pair per row ----
    #pragma unroll
    for (int t = 0; t < 4; ++t)
        #pragma unroll
        for (int r = 0; r < 4; ++r) {
            float tv = tt[t][r], dv = dd[t][r];
            tv += __shfl_xor(tv, 1); dv += __shfl_xor(dv, 1);
            tv += __shfl_xor(tv, 2); dv += __shfl_xor(dv, 2);
            tv += __shfl_xor(tv, 4); dv += __shfl_xor(dv, 4);
            tv += __shfl_xor(tv, 8); dv += __shfl_xor(dv, 8);
            if (l16 == 0) {
                int row = rowBase + t * 16 + quad * 4 + r;
                float li = lh[row].x;
                // pos (incl. diagonal) = (tot + li*dif_raw) / 2 since labels are +-1
                atomicAdd(&pos_sum[row], 0.5f * (tv + li * dv));
                atomicAdd(&tot_sum[row], tv);
            }
        }
}

// ---------------- fin ----------------
__global__ __launch_bounds__(1024) void fin_kernel(
    const float* __restrict__ pos_sum, const float* __restrict__ tot_sum,
    const float* __restrict__ sd, const float2* __restrict__ lh,
    float* __restrict__ out, int B)
{
    __shared__ float ssum[16], scnt[16];
    float sum = 0.0f, cnt = 0.0f;
    for (int i = threadIdx.x; i < B; i += 1024) {
        float posr = pos_sum[i];
        float neg  = tot_sum[i] - posr;   // diagonal cancels
        float diag = (lh[i].y != 0.0f) ? __builtin_amdgcn_exp2f(sd[i]) : 0.0f;
        float pos  = posr - diag;
        if (pos > 0.0f && neg > 0.0f) {
            sum += logf((pos + neg + 1e-8f) / pos);
            cnt += 1.0f;
        }
    }
    #pragma unroll
    for (int m = 32; m; m >>= 1) {
        sum += __shfl_xor(sum, m);
        cnt += __shfl_xor(cnt, m);
    }
    int wave = threadIdx.x >> 6, lane = threadIdx.x & 63;
    if (lane == 0) { ssum[wave] = sum; scnt[wave] = cnt; }
    __syncthreads();
    if (threadIdx.x == 0) {
        float S = 0.0f, C = 0.0f;
        #pragma unroll
        for (int w = 0; w < 16; ++w) { S += ssum[w]; C += scnt[w]; }
        out[0] = (C > 0.0f) ? S / fmaxf(C, 1.0f) : 0.0f;
    }
}

extern "C" void kernel_launch(void* const* d_in, const int* in_sizes, int n_in,
                              void* d_out, int out_size, void* d_ws, size_t ws_size,
                              hipStream_t stream) {
    const float* emb    = (const float*)d_in[0];
    const int*   labels = (const int*)d_in[1];
    const float* conf   = (const float*)d_in[2];
    float* out = (float*)d_out;
    int B = in_sizes[1];   // 8192

    char* ws = (char*)d_ws;
    size_t off = 0;
    short*  Ea  = (short*)(ws + off);  off += (size_t)B * DDIM * 2;
    short*  Eb  = (short*)(ws + off);  off += (size_t)B * DDIM * 2;
    float2* lhp = (float2*)(ws + off); off += (size_t)B * 8;
    float*  sd  = (float*)(ws + off);  off += (size_t)B * 4;
    float*  pos = (float*)(ws + off);  off += (size_t)B * 4;
    float*  tot = (float*)(ws + off);  off += (size_t)B * 4;

    prep_kernel<<<B / 4, 256, 0, stream>>>(emb, labels, conf, Ea, Eb, lhp, sd, pos, tot, B);

    int rowBlocks = B / 256;             // 32
    int colChunks = B / (GROUPS * 128);  // 16 -> 512 blocks = 2 blocks/CU
    sim_kernel<<<dim3(rowBlocks, colChunks), 256, 0, stream>>>(Ea, Eb, lhp, pos, tot);

    fin_kernel<<<1, 1024, 0, stream>>>(pos, tot, sd, lhp, out, B);
}

// Round 5
// 100.597 us; speedup vs baseline: 1.2910x; 1.2910x over previous
//
#include <hip/hip_runtime.h>
#include <cstddef>

// InfoNCE loss, B=8192, D=128.
// prep: normalize + bf16 cast + per-row (label,conf-sign) + per-col character
//       coefficients (cm, cm*u, w, u*w) + self-dot
// sim:  dbuf global_load_lds staged bf16 MFMA E.E^T (r1-verified swizzle),
//       character-sum epilogue T/U/W/X (1 exp + 4 fma per element, no masks).
//       Register budget engineered to ~105 < 128: 2 row-tiles, ZERO staging
//       regs (rounds 1-4 all lost to spills: allocator lands at ~budget/2).
// fin:  per-row pos/neg from character sums, mean over valid rows

#define DDIM 128
#define TEMP_SCALE 14.4269504088896340736f  // (1/0.1) * log2(e), folded into A-side
#define GROUPS 4                            // 128-col groups per block (y-chunk = 512 cols)

typedef short s8bf __attribute__((ext_vector_type(8)));   // 8 bf16 (4 VGPRs)
typedef float f32x4 __attribute__((ext_vector_type(4)));

typedef __attribute__((address_space(1))) void gas_void;
typedef __attribute__((address_space(3))) void las_void;

__device__ __forceinline__ void gload_lds16(const void* g, void* l) {
    __builtin_amdgcn_global_load_lds((gas_void*)g, (las_void*)l, 16, 0, 0);
}

__device__ __forceinline__ unsigned short f2bf(float f) {
    unsigned int u = __float_as_uint(f);
    u += 0x7fffu + ((u >> 16) & 1u);
    return (unsigned short)(u >> 16);
}
__device__ __forceinline__ float bf2f(unsigned short h) {
    return __uint_as_float(((unsigned int)h) << 16);
}

// ---------------- prep: one wave per row ----------------
__global__ __launch_bounds__(256) void prep_kernel(
    const float* __restrict__ emb, const int* __restrict__ labels,
    const float* __restrict__ conf,
    short* __restrict__ Ea,    // bf16(SCALE * e)  (A-side, pre-scaled)
    short* __restrict__ Eb,    // bf16(e)          (B-side)
    float2* __restrict__ lh,   // (label +-1, conf-sign) for fin
    float4* __restrict__ colc, // (cm, cm*u, w, u*w) column characters
    float* __restrict__ sd,    // scaled self-dot (bf16-rounded), diag of sim*SCALE
    float* __restrict__ sT, float* __restrict__ sU,
    float* __restrict__ sW, float* __restrict__ sX, int B)
{
    int wave = threadIdx.x >> 6;
    int lane = threadIdx.x & 63;
    int row  = blockIdx.x * 4 + wave;
    if (row >= B) return;

    float2 x = ((const float2*)(emb + (size_t)row * DDIM))[lane];
    float ss = x.x * x.x + x.y * x.y;
    #pragma unroll
    for (int m = 32; m; m >>= 1) ss += __shfl_xor(ss, m);
    float inv = 1.0f / fmaxf(sqrtf(ss), 1e-12f);

    float e0 = x.x * inv, e1 = x.y * inv;
    unsigned short ea0 = f2bf(TEMP_SCALE * e0), ea1 = f2bf(TEMP_SCALE * e1);
    unsigned short eb0 = f2bf(e0),              eb1 = f2bf(e1);
    *(ushort2*)(Ea + (size_t)row * DDIM + lane * 2) = make_ushort2(ea0, ea1);
    *(ushort2*)(Eb + (size_t)row * DDIM + lane * 2) = make_ushort2(eb0, eb1);

    float p = bf2f(ea0) * bf2f(eb0) + bf2f(ea1) * bf2f(eb1);
    #pragma unroll
    for (int m = 32; m; m >>= 1) p += __shfl_xor(p, m);

    if (lane == 0) {
        sd[row] = p;
        float l = labels[row] ? 1.0f : -1.0f;
        float c = conf[row];
        float h = (c > 0.0f) ? 1.0f : ((c < 0.0f) ? -1.0f : 0.0f);
        lh[row] = make_float2(l, h);
        float cm = (h != 0.0f) ? 1.0f : 0.0f;
        colc[row] = make_float4(cm, l * cm, h, l * h);
        sT[row] = 0.0f; sU[row] = 0.0f; sW[row] = 0.0f; sX[row] = 0.0f;
    }
}

// ---------------- sim ----------------
// Block = 256 thr = 4 waves, owns 128 rows (wave w -> rows w*32..w*32+31, 2 row-tiles).
// Cols: 16 y-chunks of 512; 4 groups of 128 cols, double-buffered via global_load_lds
// into XOR-swizzled linear LDS (32 KB/buffer). LDS offset L holds global byte
// L ^ ((L>>8 & 7)<<4) (involution; r1-verified correct). Reads apply the same XOR:
// per quarter-wave the 16 lanes hit 8 distinct 16B slots = free 2-way.
// Epilogue: e = exp2(acc); T += cm*e; U += cu*e; W += w*e; X += uw*e.
#define MFMA16(A, Bf, C) __builtin_amdgcn_mfma_f32_16x16x32_bf16((A), (Bf), (C), 0, 0, 0)

__device__ __forceinline__ void stage_group(const short* __restrict__ Eb, int colbase,
                                            short* tilebuf, int wave, int lane) {
    const char* gb = (const char*)Eb + (size_t)colbase * 256;
    char* lb = (char*)tilebuf;
    #pragma unroll
    for (int i = 0; i < 8; ++i) {
        int L  = i * 4096 + wave * 1024 + lane * 16;
        int Ls = L ^ (((L >> 8) & 7) << 4);   // inverse-swizzled source
        gload_lds16(gb + Ls, lb + i * 4096 + wave * 1024);
    }
}

__global__ __launch_bounds__(256, 2) void sim_kernel(
    const short* __restrict__ Ea, const short* __restrict__ Eb,
    const float4* __restrict__ colcg,
    float* __restrict__ sT, float* __restrict__ sU,
    float* __restrict__ sW, float* __restrict__ sX)
{
    __shared__ short tile[2][128 * 128];     // 2 x 32 KB, swizzled, linear for gload_lds
    __shared__ float4 cc[GROUPS * 128];      // 8 KB column characters

    const int lane = threadIdx.x & 63;
    const int wave = threadIdx.x >> 6;
    const int l16  = lane & 15;
    const int quad = lane >> 4;
    const int rowBase = blockIdx.x * 128 + wave * 32;   // 2 row-tiles

    // A fragments (loop-invariant): A[m=l16][k=quad*8+j], contiguous b128
    s8bf a0[4], a1[4];
    #pragma unroll
    for (int k = 0; k < 4; ++k) {
        a0[k] = *(const s8bf*)(Ea + (size_t)(rowBase +      l16) * DDIM + k * 32 + quad * 8);
        a1[k] = *(const s8bf*)(Ea + (size_t)(rowBase + 16 + l16) * DDIM + k * 32 + quad * 8);
    }

    // character sums; C/D layout: col = lane&15, row = quad*4 + reg
    float accT[2][4], accU[2][4], accW[2][4], accX[2][4];
    #pragma unroll
    for (int t = 0; t < 2; ++t)
        #pragma unroll
        for (int r = 0; r < 4; ++r) {
            accT[t][r] = 0.0f; accU[t][r] = 0.0f;
            accW[t][r] = 0.0f; accX[t][r] = 0.0f;
        }

    const int c0base = blockIdx.y * (GROUPS * 128);

    // hoist all 512 column characters once (visible after the prologue barrier)
    cc[threadIdx.x]       = colcg[c0base + threadIdx.x];
    cc[256 + threadIdx.x] = colcg[c0base + 256 + threadIdx.x];

    stage_group(Eb, c0base, &tile[0][0], wave, lane);
    __syncthreads();   // drains vmcnt: buf0 staged; cc visible

    int cur = 0;
    const int swz = (l16 & 7) << 4;
    for (int g = 0; g < GROUPS; ++g) {
        // issue next group's DMA first; completes during compute, drained by barrier
        if (g + 1 < GROUPS)
            stage_group(Eb, c0base + (g + 1) * 128, &tile[cur ^ 1][0], wave, lane);
        __builtin_amdgcn_sched_barrier(0);

        const char* tb0 = (const char*)&tile[cur][0];
        #pragma unroll
        for (int ct = 0; ct < 8; ++ct) {
            const char* tb = tb0 + (ct * 16 + l16) * 256;
            s8bf b0 = *(const s8bf*)(tb + ((  0 + quad * 16) ^ swz));
            s8bf b1 = *(const s8bf*)(tb + (( 64 + quad * 16) ^ swz));
            s8bf b2 = *(const s8bf*)(tb + ((128 + quad * 16) ^ swz));
            s8bf b3 = *(const s8bf*)(tb + ((192 + quad * 16) ^ swz));
            float4 c4 = cc[g * 128 + ct * 16 + l16];

            f32x4 acc0 = {0.f, 0.f, 0.f, 0.f}, acc1 = {0.f, 0.f, 0.f, 0.f};
            acc0 = MFMA16(a0[0], b0, acc0);
            acc0 = MFMA16(a0[1], b1, acc0);
            acc0 = MFMA16(a0[2], b2, acc0);
            acc0 = MFMA16(a0[3], b3, acc0);
            acc1 = MFMA16(a1[0], b0, acc1);
            acc1 = MFMA16(a1[1], b1, acc1);
            acc1 = MFMA16(a1[2], b2, acc1);
            acc1 = MFMA16(a1[3], b3, acc1);

            #pragma unroll
            for (int r = 0; r < 4; ++r) {
                float e0 = __builtin_amdgcn_exp2f(acc0[r]);
                accT[0][r] = fmaf(c4.x, e0, accT[0][r]);
                accU[0][r] = fmaf(c4.y, e0, accU[0][r]);
                accW[0][r] = fmaf(c4.z, e0, accW[0][r]);
                accX[0][r] = fmaf(c4.w, e0, accX[0][r]);
                float e1 = __builtin_amdgcn_exp2f(acc1[r]);
                accT[1][r] = fmaf(c4.x, e1, accT[1][r]);
                accU[1][r] = fmaf(c4.y, e1, accU[1][r]);
                accW[1][r] = fmaf(c4.z, e1, accW[1][r]);
                accX[1][r] = fmaf(c4.w, e1, accX[1][r]);
            }
        }
        __syncthreads();   // drains next-group DMA; closes read window on tile[cur]
        cur ^= 1;
    }

    // ---- reduce over the 16 column-lanes, 4 atomics per row ----
    #pragma unroll
    for (int t = 0; t < 2; ++t)
        #pragma unroll
        for (int r = 0; r < 4; ++r) {
            float T = accT[t][r], U = accU[t][r], W = accW[t][r], X = accX[t][r];
            #pragma unroll
            for (int m = 1; m < 16; m <<= 1) {
                T += __shfl_xor(T, m); U += __shfl_xor(U, m);
                W += __shfl_xor(W, m); X += __shfl_xor(X, m);
            }
            if (l16 == 0) {
                int row = rowBase + t * 16 + quad * 4 + r;
                atomicAdd(&sT[row], T); atomicAdd(&sU[row], U);
                atomicAdd(&sW[row], W); atomicAdd(&sX[row], X);
            }
        }
}

// ---------------- fin ----------------
__global__ __launch_bounds__(1024) void fin_kernel(
    const float* __restrict__ sT, const float* __restrict__ sU,
    const float* __restrict__ sW, const float* __restrict__ sX,
    const float* __restrict__ sd, const float2* __restrict__ lh,
    float* __restrict__ out, int B)
{
    __shared__ float ssum[16], scnt[16];
    float sum = 0.0f, cnt = 0.0f;
    for (int i = threadIdx.x; i < B; i += 1024) {
        float2 p = lh[i];
        float s = p.x, sg = p.y;
        if (sg != 0.0f) {
            float P = fmaf(sg, sW[i], sT[i]);        // T + sg*W
            float Q = s * fmaf(sg, sX[i], sU[i]);    // s*(U + sg*X)
            float pos = 0.25f * (P + Q) - __builtin_amdgcn_exp2f(sd[i]);  // drop diag
            float neg = 0.25f * (P - Q);
            if (pos > 0.0f && neg > 0.0f) {
                sum += logf((pos + neg + 1e-8f) / pos);
                cnt += 1.0f;
            }
        }
    }
    #pragma unroll
    for (int m = 32; m; m >>= 1) {
        sum += __shfl_xor(sum, m);
        cnt += __shfl_xor(cnt, m);
    }
    int wave = threadIdx.x >> 6, lane = threadIdx.x & 63;
    if (lane == 0) { ssum[wave] = sum; scnt[wave] = cnt; }
    __syncthreads();
    if (threadIdx.x == 0) {
        float S = 0.0f, C = 0.0f;
        #pragma unroll
        for (int w = 0; w < 16; ++w) { S += ssum[w]; C += scnt[w]; }
        out[0] = (C > 0.0f) ? S / fmaxf(C, 1.0f) : 0.0f;
    }
}

extern "C" void kernel_launch(void* const* d_in, const int* in_sizes, int n_in,
                              void* d_out, int out_size, void* d_ws, size_t ws_size,
                              hipStream_t stream) {
    const float* emb    = (const float*)d_in[0];
    const int*   labels = (const int*)d_in[1];
    const float* conf   = (const float*)d_in[2];
    float* out = (float*)d_out;
    int B = in_sizes[1];   // 8192

    char* ws = (char*)d_ws;
    size_t off = 0;
    short*  Ea  = (short*)(ws + off);  off += (size_t)B * DDIM * 2;
    short*  Eb  = (short*)(ws + off);  off += (size_t)B * DDIM * 2;
    float2* lhp = (float2*)(ws + off); off += (size_t)B * 8;
    float4* clc = (float4*)(ws + off); off += (size_t)B * 16;
    float*  sd  = (float*)(ws + off);  off += (size_t)B * 4;
    float*  sT  = (float*)(ws + off);  off += (size_t)B * 4;
    float*  sU  = (float*)(ws + off);  off += (size_t)B * 4;
    float*  sW  = (float*)(ws + off);  off += (size_t)B * 4;
    float*  sX  = (float*)(ws + off);  off += (size_t)B * 4;

    prep_kernel<<<B / 4, 256, 0, stream>>>(emb, labels, conf, Ea, Eb, lhp, clc, sd,
                                           sT, sU, sW, sX, B);

    int rowBlocks = B / 128;             // 64
    int colChunks = B / (GROUPS * 128);  // 16 -> 1024 blocks
    sim_kernel<<<dim3(rowBlocks, colChunks), 256, 0, stream>>>(Ea, Eb, clc, sT, sU, sW, sX);

    fin_kernel<<<1, 1024, 0, stream>>>(sT, sU, sW, sX, sd, lhp, out, B);
}